// Round 6
// baseline (111.563 us; speedup 1.0000x reference)
//
#include <hip/hip_runtime.h>
#include <cfloat>

// Problem constants (fixed by reference): B=4, N=M=8192, D=3, fp32.
#define BB    4
#define NN    8192
#define MM    8192
#define NPTS  (BB * NN)         // 32768 points per tensor
#define QT    4                 // queries per thread (register tile)
#define BLK   256
#define QB    (BLK * QT)        // 1024 queries per block
#define QBLKS (NPTS / QB)       // 32 query-blocks per direction
#define SEG   32                // target segments per batch (grid = 2*32*32 = 2048)
#define TSEG  (MM / SEG)        // 256 targets per block (4 KB, K$-resident)

// Monotone float->uint mapping so uint atomicMin == float min (handles negatives).
__device__ __forceinline__ unsigned int fmap(float f) {
    unsigned int u = __float_as_uint(f);
    return (u & 0x80000000u) ? ~u : (u | 0x80000000u);
}
__device__ __forceinline__ float funmap(unsigned int u) {
    u = (u & 0x80000000u) ? (u & 0x7FFFFFFFu) : ~u;
    return __uint_as_float(u);
}

// Accumulating 3-input min, tied to the accumulator register (no result mov).
__device__ __forceinline__ void min3_acc(float& m, float a, float b) {
    asm("v_min3_f32 %0, %0, %1, %2" : "+v"(m) : "v"(a), "v"(b));
}

// Prep: pack (x,y,z,||p||^2/2) float4s for both tensors (enables uniform
// s_load_dwordx4 target broadcasts in main), init mins/tickets/out.
__global__ void chamfer_prep(const float* __restrict__ gts,
                             const float* __restrict__ preds,
                             float4* __restrict__ pg, float4* __restrict__ pp,
                             unsigned int* __restrict__ mins,
                             unsigned int* __restrict__ tickets,
                             float* __restrict__ out, int out_size) {
    int idx = blockIdx.x * blockDim.x + threadIdx.x;   // 0 .. 2*NPTS-1
    const float* src = (idx < NPTS) ? gts : preds;
    int k = (idx < NPTS) ? idx : idx - NPTS;
    float x = src[k * 3 + 0], y = src[k * 3 + 1], z = src[k * 3 + 2];
    float4 v = make_float4(x, y, z, 0.5f * (x * x + y * y + z * z));
    if (idx < NPTS) pg[k] = v; else pp[k] = v;
    mins[idx] = 0xFFFFFFFFu;
    if (idx < 2 * QBLKS) tickets[idx] = 0u;
    if (idx < out_size) out[idx] = 0.f;
}

// Each thread: QT=4 query points vs TSEG=256 targets.
// Rounds 0/4/5 lesson: with targets staged in LDS, the kernel sits on the
// ds_read_b128 throughput floor (256 reads/wave x 12 cyc x 32 waves/CU
// ~ 41 us) — VALU-count changes were null. Targets are WAVE-UNIFORM, so
// read them via scalar loads (uniform index into packed float4 -> SMEM/K$)
// and broadcast from SGPRs into the fma chain. No LDS in the hot loop.
//
// Fused reduction without __threadfence (round-3 lesson: threadfence =
// L2 writeback+invalidate, ~115 us over 2048 blocks). Ordering needs only:
// my atomicMins complete (s_waitcnt vmcnt(0)) for all waves (__syncthreads)
// before the ticket increment; readers use identity-atomicMin RMWs.
__global__ void __launch_bounds__(256, 8) chamfer_main(
        const float4* __restrict__ pg, const float4* __restrict__ pp,
        unsigned int* __restrict__ mins, unsigned int* __restrict__ tickets,
        float* __restrict__ out) {
    __shared__ float red[4];
    __shared__ unsigned int done;

    int bid  = blockIdx.x;          // grid = 2048
    int dir  = bid >> 10;           // 1024 blocks per direction
    int rest = bid & 1023;
    int qblk = rest >> 5;           // 32 query-blocks per direction
    int seg  = rest & 31;           // 32 target segments
    int b    = qblk >> 3;           // 8 query-blocks per batch (uniform per block)

    const float4* __restrict__ Q = dir ? pp : pg;
    const float4* __restrict__ T = dir ? pg : pp;
    const float4* __restrict__ t = T + b * MM + seg * TSEG;   // uniform base

    int q0 = qblk * QB + threadIdx.x;            // query index within direction
    float qx[QT], qy[QT], qz[QT], qw[QT], m[QT];
    #pragma unroll
    for (int k = 0; k < QT; ++k) {
        float4 q = Q[q0 + 256 * k];              // coalesced dwordx4
        qx[k] = q.x; qy[k] = q.y; qz[k] = q.z; qw[k] = q.w;
        m[k]  = FLT_MAX;
    }

    #pragma unroll 4
    for (int j = 0; j < TSEG; j += 2) {
        float4 t0 = t[j], t1 = t[j + 1];         // uniform -> s_load, SGPR bcast
        #pragma unroll
        for (int k = 0; k < QT; ++k) {
            float s0 = fmaf(-qx[k], t0.x,
                       fmaf(-qy[k], t0.y,
                       fmaf(-qz[k], t0.z, t0.w)));
            float s1 = fmaf(-qx[k], t1.x,
                       fmaf(-qy[k], t1.y,
                       fmaf(-qz[k], t1.z, t1.w)));
            min3_acc(m[k], s0, s1);              // tied v_min3_f32
        }
    }

    #pragma unroll
    for (int k = 0; k < QT; ++k)
        atomicMin(&mins[dir * NPTS + q0 + 256 * k], fmap(m[k]));

    // --- fused reduction: last block of this (dir,qblk) group sums it ---
    asm volatile("s_waitcnt vmcnt(0)" ::: "memory");  // my atomics complete
    __syncthreads();                                  // ... for ALL waves
    if (threadIdx.x == 0)
        done = atomicAdd(&tickets[dir * QBLKS + qblk], 1u);
    __syncthreads();
    if (done != SEG - 1) return;

    float val = 0.f;
    #pragma unroll
    for (int k = 0; k < QT; ++k) {
        // identity atomicMin = coherent read of the final minimum
        unsigned int u = atomicMin(&mins[dir * NPTS + q0 + 256 * k], 0xFFFFFFFFu);
        val += 2.0f * (funmap(u) + qw[k]);       // q.w = ||q||^2/2, in register
    }

    #pragma unroll
    for (int off = 32; off > 0; off >>= 1)
        val += __shfl_down(val, off, 64);
    int lane = threadIdx.x & 63;
    int w_id = threadIdx.x >> 6;
    if (lane == 0) red[w_id] = val;
    __syncthreads();
    if (threadIdx.x == 0)
        atomicAdd(out, red[0] + red[1] + red[2] + red[3]);
}

extern "C" void kernel_launch(void* const* d_in, const int* in_sizes, int n_in,
                              void* d_out, int out_size, void* d_ws, size_t ws_size,
                              hipStream_t stream) {
    const float* gts   = (const float*)d_in[0];
    const float* preds = (const float*)d_in[1];
    float* out = (float*)d_out;

    char* ws = (char*)d_ws;
    float4* pg = (float4*)ws;                                          // 512 KB
    float4* pp = (float4*)(ws + (size_t)NPTS * 16);                    // 512 KB
    unsigned int* mins    = (unsigned int*)(ws + (size_t)2 * NPTS * 16); // 256 KB
    unsigned int* tickets = (unsigned int*)(ws + (size_t)2 * NPTS * 16 + (size_t)2 * NPTS * 4);

    chamfer_prep<<<(2 * NPTS) / 256, 256, 0, stream>>>(gts, preds, pg, pp,
                                                       mins, tickets, out, out_size);
    chamfer_main<<<2 * QBLKS * SEG, 256, 0, stream>>>(pg, pp, mins, tickets, out);
}

// Round 7
// 97.495 us; speedup vs baseline: 1.1443x; 1.1443x over previous
//
#include <hip/hip_runtime.h>
#include <cfloat>

// Problem constants (fixed by reference): B=4, N=M=8192, D=3, fp32.
#define BB    4
#define NN    8192
#define MM    8192
#define NPTS  (BB * NN)         // 32768 points per tensor
#define QT    8                 // queries per thread — amortizes LDS reads:
                                // LDS cyc/pair = (2 reads/16 pairs)*12 = 1.5
                                // < VALU 3.5/2 = 1.75  -> VALU-bound
#define BLK   256
#define QB    (BLK * QT)        // 2048 queries per block
#define QBLKS (NPTS / QB)       // 16 query-blocks per direction
#define SEG   64                // target segments (grid = 2*16*64 = 2048, 8/CU)
#define TSEG  (MM / SEG)        // 128 targets per block (2 KB LDS)

// Monotone float->uint mapping so uint atomicMin == float min (handles negatives).
__device__ __forceinline__ unsigned int fmap(float f) {
    unsigned int u = __float_as_uint(f);
    return (u & 0x80000000u) ? ~u : (u | 0x80000000u);
}
__device__ __forceinline__ float funmap(unsigned int u) {
    u = (u & 0x80000000u) ? (u & 0x7FFFFFFFu) : ~u;
    return __uint_as_float(u);
}

// Accumulating 3-input min, tied to the accumulator register (no result mov).
__device__ __forceinline__ void min3_acc(float& m, float a, float b) {
    asm("v_min3_f32 %0, %0, %1, %2" : "+v"(m) : "v"(a), "v"(b));
}

// Trivial init: mins = +inf (ordered-uint max), tickets = 0, out = 0.
// Workspace is re-poisoned between iterations, so this must run every time.
__global__ void chamfer_init(unsigned int* __restrict__ mins,
                             unsigned int* __restrict__ tickets,
                             float* __restrict__ out, int out_size) {
    int i = blockIdx.x * blockDim.x + threadIdx.x;       // 16384 threads
    ((uint4*)mins)[i] = make_uint4(~0u, ~0u, ~0u, ~0u);  // 65536 uints = 256 KB
    if (i < 2 * QBLKS) tickets[i] = 0u;                  // 32 group counters
    if (i < out_size) out[i] = 0.f;
}

// Each thread: QT=8 query points vs TSEG=128 targets staged in LDS.
// Tracks min_j( ||t||^2/2 - q.t ); final value = 2*(min + ||q||^2/2).
//
// Pipe model (rounds 0-6): per CU, VALU = 2 instr/cyc (4 SIMDs), LDS pipe =
// 1 ds_read_b128 / 12 cyc SHARED by the 4 SIMDs. At QT=4 the LDS stream was
// the roof (3.0 cyc/pair vs VALU 1.75) — min3 gains were null, scalar-pipe
// move was latency-bound. QT=8 halves reads/pair -> VALU-bound.
//
// Fused reduction without __threadfence (round-3 lesson: threadfence =
// L2 writeback+invalidate, ~115 us over 2048 blocks). Ordering: my block's
// atomicMins complete (s_waitcnt vmcnt(0)) for all waves (__syncthreads)
// before the ticket add; readers use identity-atomicMin RMWs (coherent).
__global__ void __launch_bounds__(256, 8) chamfer_main(
        const float* __restrict__ gts, const float* __restrict__ preds,
        unsigned int* __restrict__ mins, unsigned int* __restrict__ tickets,
        float* __restrict__ out) {
    __shared__ float4 st[TSEG];
    __shared__ float red[4];
    __shared__ unsigned int done;

    int bid  = blockIdx.x;          // grid = 2048
    int dir  = bid >> 10;           // 1024 blocks per direction
    int rest = bid & 1023;
    int qblk = rest >> 6;           // 16 query-blocks per direction
    int seg  = rest & 63;           // 64 target segments
    int b    = qblk >> 2;           // 4 query-blocks per batch (uniform per block)

    const float* __restrict__ Q = dir ? preds : gts;
    const float* __restrict__ T = dir ? gts : preds;
    const float* __restrict__ tp = T + (size_t)(b * MM + seg * TSEG) * 3;

    // Stage this segment's targets from raw float3, computing w on the fly.
    if (threadIdx.x < TSEG) {
        int j = threadIdx.x;
        float x = tp[3*j + 0], y = tp[3*j + 1], z = tp[3*j + 2];
        st[j] = make_float4(x, y, z, 0.5f * (x*x + y*y + z*z));
    }

    int q0 = qblk * QB + threadIdx.x;            // query index within direction
    const float* __restrict__ qp = Q + (size_t)q0 * 3;
    float qx[QT], qy[QT], qz[QT], m[QT];
    #pragma unroll
    for (int k = 0; k < QT; ++k) {
        qx[k] = qp[3*(256*k) + 0];
        qy[k] = qp[3*(256*k) + 1];
        qz[k] = qp[3*(256*k) + 2];
        m[k]  = FLT_MAX;
    }
    __syncthreads();

    #pragma unroll 4
    for (int j = 0; j < TSEG; j += 2) {
        float4 t0 = st[j], t1 = st[j+1];         // broadcast ds_read_b128 x2
        #pragma unroll
        for (int k = 0; k < QT; ++k) {
            float s0 = fmaf(-qx[k], t0.x,
                       fmaf(-qy[k], t0.y,
                       fmaf(-qz[k], t0.z, t0.w)));
            float s1 = fmaf(-qx[k], t1.x,
                       fmaf(-qy[k], t1.y,
                       fmaf(-qz[k], t1.z, t1.w)));
            min3_acc(m[k], s0, s1);              // tied v_min3_f32
        }
    }

    #pragma unroll
    for (int k = 0; k < QT; ++k)
        atomicMin(&mins[dir * NPTS + q0 + 256*k], fmap(m[k]));

    // --- fused reduction: last block of this (dir,qblk) group sums it ---
    asm volatile("s_waitcnt vmcnt(0)" ::: "memory");  // my atomics complete
    __syncthreads();                                  // ... for ALL waves
    if (threadIdx.x == 0)
        done = atomicAdd(&tickets[dir * QBLKS + qblk], 1u);
    __syncthreads();
    if (done != SEG - 1) return;

    float val = 0.f;
    #pragma unroll
    for (int k = 0; k < QT; ++k) {
        // identity atomicMin = coherent read of the final minimum
        unsigned int u = atomicMin(&mins[dir * NPTS + q0 + 256*k], 0xFFFFFFFFu);
        // reload q coords (L2-hot); keeps hot-loop register liveness short
        float x = qp[3*(256*k) + 0];
        float y = qp[3*(256*k) + 1];
        float z = qp[3*(256*k) + 2];
        val += 2.0f * (funmap(u) + 0.5f * (x*x + y*y + z*z));
    }

    #pragma unroll
    for (int off = 32; off > 0; off >>= 1)
        val += __shfl_down(val, off, 64);
    int lane = threadIdx.x & 63;
    int w_id = threadIdx.x >> 6;
    if (lane == 0) red[w_id] = val;
    __syncthreads();
    if (threadIdx.x == 0)
        atomicAdd(out, red[0] + red[1] + red[2] + red[3]);
}

extern "C" void kernel_launch(void* const* d_in, const int* in_sizes, int n_in,
                              void* d_out, int out_size, void* d_ws, size_t ws_size,
                              hipStream_t stream) {
    const float* gts   = (const float*)d_in[0];
    const float* preds = (const float*)d_in[1];
    float* out = (float*)d_out;

    unsigned int* mins    = (unsigned int*)d_ws;                       // 256 KB
    unsigned int* tickets = (unsigned int*)((char*)d_ws + (size_t)2 * NPTS * 4);

    chamfer_init<<<64, 256, 0, stream>>>(mins, tickets, out, out_size);
    chamfer_main<<<2 * QBLKS * SEG, 256, 0, stream>>>(gts, preds, mins, tickets, out);
}